// Round 14
// baseline (54.327 us; speedup 1.0000x reference)
//
#include <hip/hip_runtime.h>
#include <hip/hip_bf16.h>
#include <math.h>

// Problem dims (fixed per reference)
#define B_DIM 32
#define C_DIM 256
#define K_DIM 32
#define N_DIM 4096   // 64*64
#define NSLICE 16    // 256-px slices (8 waves x 32 px)
#define RSD 34       // dword stride per c-pair row (32 px + 2 pad)

typedef short v8s __attribute__((ext_vector_type(8)));   // 8 bf16
typedef float v4f __attribute__((ext_vector_type(4)));   // MFMA acc

// ws float offsets — every slot overwritten each call, no zeroing, no atomics
//   [0,      131072)  Spart [B][16][C]
//   [131072, 147456)  a_part[B][16][K]
#define WS_SPART 0
#define WS_APART 131072

__device__ __forceinline__ unsigned pack_bf16(float lo, float hi) {
    union { __hip_bfloat16 h; unsigned short u; } a, b;
    a.h = __float2bfloat16(lo);
    b.h = __float2bfloat16(hi);
    return ((unsigned)b.u << 16) | a.u;
}

__global__ __launch_bounds__(512, 4)
void ce_main(const float* __restrict__ x,
             const float* __restrict__ cw,
             const float* __restrict__ scale,
             float* __restrict__ Spart,
             float* __restrict__ a_part) {
    __shared__ float buf[2][8][16 * RSD];  // 34.8 KB: per-wave double-buffered tiles
    __shared__ unsigned cwl[K_DIM][132];   // 16.9 KB cw bf16-pairs (uint4-only access)
    __shared__ float sA[8][C_DIM];         // 8 KB per-wave S (fp32, from registers)
    __shared__ float awv[8][K_DIM];        // per-wave a partials
    __shared__ float f2s[8][32];           // per-wave f2 (32 px each)
    __shared__ float csl[64];              // c2[32] ++ scale[32]

    const int tid   = threadIdx.x;
    const int wave  = tid >> 6;    // 0..7
    const int lane  = tid & 63;
    const int g     = lane >> 4;   // consume role: 16-lane group
    const int m     = lane & 15;
    const int r0    = lane >> 3;   // load role: c-pair row 0..7 (also row+8)
    const int qd    = lane & 7;    // load role: px-quad 0..7
    const int slice = blockIdx.x;  // 0..15
    const int b     = blockIdx.y;  // 0..31

    const float* xw = x + (size_t)b * C_DIM * N_DIM + slice * 256 + wave * 32;

    // ---- step-0 x loads FIRST (HBM latency hides under cw staging) ----
    float4 xv[4];
    #pragma unroll
    for (int j = 0; j < 2; ++j)
        #pragma unroll
        for (int rr = 0; rr < 2; ++rr)
            xv[2 * j + rr] = *(const float4*)(xw + (size_t)(2 * (r0 + 8 * j) + rr) * N_DIM + 4 * qd);

    // ---- fused prep: cw fp32 -> bf16 LDS + c2 + scale (once per block) ----
    {
        const int r = tid >> 4, c16 = tid & 15;   // k-row 0..31, 16-float chunk
        float4 cv[4];
        #pragma unroll
        for (int j = 0; j < 4; ++j)
            cv[j] = ((const float4*)(cw + (size_t)r * C_DIM + c16 * 16))[j];
        float sq = 0.f;
        #pragma unroll
        for (int j = 0; j < 4; ++j) {
            sq = fmaf(cv[j].x, cv[j].x, sq);
            sq = fmaf(cv[j].y, cv[j].y, sq);
            sq = fmaf(cv[j].z, cv[j].z, sq);
            sq = fmaf(cv[j].w, cv[j].w, sq);
        }
        sq += __shfl_xor(sq, 1);
        sq += __shfl_xor(sq, 2);
        sq += __shfl_xor(sq, 4);
        sq += __shfl_xor(sq, 8);
        if (c16 == 0) csl[r] = sq;
        if (tid < K_DIM) csl[32 + tid] = scale[tid];
        uint4 o0, o1;
        o0.x = pack_bf16(cv[0].x, cv[0].y); o0.y = pack_bf16(cv[0].z, cv[0].w);
        o0.z = pack_bf16(cv[1].x, cv[1].y); o0.w = pack_bf16(cv[1].z, cv[1].w);
        o1.x = pack_bf16(cv[2].x, cv[2].y); o1.y = pack_bf16(cv[2].z, cv[2].w);
        o1.z = pack_bf16(cv[3].x, cv[3].y); o1.w = pack_bf16(cv[3].z, cv[3].w);
        *(uint4*)&cwl[r][8 * c16]     = o0;
        *(uint4*)&cwl[r][8 * c16 + 4] = o1;
    }
    __syncthreads();

    float* b0 = &buf[0][wave][0];
    float* b1 = &buf[1][wave][0];

    v4f acc[2][2];
    #pragma unroll
    for (int u = 0; u < 2; ++u)
        #pragma unroll
        for (int t = 0; t < 2; ++t) acc[u][t] = (v4f){0.f, 0.f, 0.f, 0.f};

    float f2q[4] = {0.f, 0.f, 0.f, 0.f};

    // pack xv -> tile bp for c-step sp: bf16 LDS tile + fp32 S rows + f2
    auto PACK = [&](float* bp, int sp) {
        unsigned* bu = (unsigned*)bp;
        float s4[4];
        #pragma unroll
        for (int j = 0; j < 2; ++j) {
            float4 ra = xv[2 * j], rb = xv[2 * j + 1];
            f2q[0] = fmaf(ra.x, ra.x, f2q[0]); f2q[0] = fmaf(rb.x, rb.x, f2q[0]);
            f2q[1] = fmaf(ra.y, ra.y, f2q[1]); f2q[1] = fmaf(rb.y, rb.y, f2q[1]);
            f2q[2] = fmaf(ra.z, ra.z, f2q[2]); f2q[2] = fmaf(rb.z, rb.z, f2q[2]);
            f2q[3] = fmaf(ra.w, ra.w, f2q[3]); f2q[3] = fmaf(rb.w, rb.w, f2q[3]);
            s4[2 * j]     = (ra.x + ra.y) + (ra.z + ra.w);
            s4[2 * j + 1] = (rb.x + rb.y) + (rb.z + rb.w);
            unsigned* dst = &bu[(r0 + 8 * j) * RSD + 4 * qd];
            dst[0] = pack_bf16(ra.x, rb.x);
            dst[1] = pack_bf16(ra.y, rb.y);
            dst[2] = pack_bf16(ra.z, rb.z);
            dst[3] = pack_bf16(ra.w, rb.w);
        }
        #pragma unroll
        for (int i = 0; i < 4; ++i) {
            s4[i] += __shfl_xor(s4[i], 1);
            s4[i] += __shfl_xor(s4[i], 2);
            s4[i] += __shfl_xor(s4[i], 4);
        }
        if (qd == 0) {
            sA[wave][32 * sp + 2 * r0]           = s4[0];
            sA[wave][32 * sp + 2 * r0 + 1]       = s4[1];
            sA[wave][32 * sp + 2 * (r0 + 8)]     = s4[2];
            sA[wave][32 * sp + 2 * (r0 + 8) + 1] = s4[3];
        }
    };

    PACK(b0, 0);

    #pragma unroll
    for (int s = 0; s < 8; ++s) {
        float* cb = (s & 1) ? b1 : b0;
        float* nb = (s & 1) ? b0 : b1;

        // issue next step's x loads (consumed by PACK below)
        if (s < 7) {
            #pragma unroll
            for (int j = 0; j < 2; ++j)
                #pragma unroll
                for (int rr = 0; rr < 2; ++rr)
                    xv[2 * j + rr] = *(const float4*)(xw +
                        (size_t)(32 * (s + 1) + 2 * (r0 + 8 * j) + rr) * N_DIM + 4 * qd);
        }

        // A-frags from LDS (k = 16u+m, c = 32s+8g..+7) + B-frags + 4 MFMA
        union { uint4 u4; v8s v; } a0, a1;
        a0.u4 = ((const uint4*)&cwl[m][0])[4 * s + g];
        a1.u4 = ((const uint4*)&cwl[16 + m][0])[4 * s + g];
        #pragma unroll
        for (int t = 0; t < 2; ++t) {
            union { unsigned d[4]; v8s v; } fb;
            #pragma unroll
            for (int h = 0; h < 4; ++h)
                fb.d[h] = ((const unsigned*)cb)[(4 * g + h) * RSD + 16 * t + m];
            acc[0][t] = __builtin_amdgcn_mfma_f32_16x16x32_bf16(a0.v, fb.v, acc[0][t], 0, 0, 0);
            acc[1][t] = __builtin_amdgcn_mfma_f32_16x16x32_bf16(a1.v, fb.v, acc[1][t], 0, 0, 0);
        }

        if (s < 7) PACK(nb, s + 1);
    }

    // ---- epilogue ----
    // f2 per px: reduce over the 8 r0-lanes sharing a px-quad
    #pragma unroll
    for (int p = 0; p < 4; ++p) {
        f2q[p] += __shfl_xor(f2q[p], 8);
        f2q[p] += __shfl_xor(f2q[p], 16);
        f2q[p] += __shfl_xor(f2q[p], 32);
    }
    if (lane < 8) {
        f2s[wave][4 * qd + 0] = f2q[0];
        f2s[wave][4 * qd + 1] = f2q[1];
        f2s[wave][4 * qd + 2] = f2q[2];
        f2s[wave][4 * qd + 3] = f2q[3];
    }

    float c2v[2][4], scv[2][4];
    #pragma unroll
    for (int u = 0; u < 2; ++u)
        #pragma unroll
        for (int r = 0; r < 4; ++r) {
            int k = 16 * u + 4 * g + r;
            c2v[u][r] = csl[k];
            scv[u][r] = csl[32 + k];
        }

    float aacc[2][4] = {{0.f,0.f,0.f,0.f},{0.f,0.f,0.f,0.f}};
    #pragma unroll
    for (int t = 0; t < 2; ++t) {
        float f2t = f2s[wave][16 * t + m];   // px = 16t + m
        float L[2][4];
        float mx = -1e30f;
        #pragma unroll
        for (int u = 0; u < 2; ++u)
            #pragma unroll
            for (int r = 0; r < 4; ++r) {
                float d2 = f2t + c2v[u][r] - 2.f * acc[u][t][r];
                float dist = sqrtf(fmaxf(d2, 0.f));
                float Lv = -dist * scv[u][r];
                L[u][r] = Lv;
                mx = fmaxf(mx, Lv);
            }
        mx = fmaxf(mx, __shfl_xor(mx, 16));
        mx = fmaxf(mx, __shfl_xor(mx, 32));
        float e[2][4], ss = 0.f;
        #pragma unroll
        for (int u = 0; u < 2; ++u)
            #pragma unroll
            for (int r = 0; r < 4; ++r) {
                e[u][r] = __expf(L[u][r] - mx);
                ss += e[u][r];
            }
        ss += __shfl_xor(ss, 16);
        ss += __shfl_xor(ss, 32);
        float inv = 1.f / ss;
        #pragma unroll
        for (int u = 0; u < 2; ++u)
            #pragma unroll
            for (int r = 0; r < 4; ++r)
                aacc[u][r] = fmaf(e[u][r], inv, aacc[u][r]);
    }

    // reduce a over the 16 m-lanes (covers this wave's 32 px)
    #pragma unroll
    for (int u = 0; u < 2; ++u)
        #pragma unroll
        for (int r = 0; r < 4; ++r) {
            float v = aacc[u][r];
            v += __shfl_xor(v, 1);
            v += __shfl_xor(v, 2);
            v += __shfl_xor(v, 4);
            v += __shfl_xor(v, 8);
            if (m == 0) awv[wave][16 * u + 4 * g + r] = v;
        }
    __syncthreads();

    // cross-wave combine: waves hold disjoint px, same c/k ranges
    if (tid < C_DIM) {
        float Ssum = 0.f;
        #pragma unroll
        for (int w = 0; w < 8; ++w) Ssum += sA[w][tid];
        Spart[((size_t)b * NSLICE + slice) * C_DIM + tid] = Ssum;
    }
    if (tid >= C_DIM && tid < C_DIM + K_DIM) {
        const int k = tid - C_DIM;
        float asum = 0.f;
        #pragma unroll
        for (int w = 0; w < 8; ++w) asum += awv[w][k];
        a_part[((size_t)b * NSLICE + slice) * K_DIM + k] = asum;
    }
}

__global__ void ce_final(float* __restrict__ out,
                         const float* __restrict__ cw,
                         const float* __restrict__ Spart,
                         const float* __restrict__ a_part) {
    __shared__ float asum[K_DIM];
    const int b = blockIdx.x;
    const int c = threadIdx.x;

    if (c < K_DIM) {
        float a = 0.f;
        #pragma unroll
        for (int s = 0; s < NSLICE; ++s)
            a += a_part[((size_t)b * NSLICE + s) * K_DIM + c];
        asum[c] = a;
    }
    __syncthreads();

    float S = 0.f;
    #pragma unroll
    for (int s = 0; s < NSLICE; ++s)
        S += Spart[((size_t)b * NSLICE + s) * C_DIM + c];

    float acc2 = 0.f;
    #pragma unroll
    for (int k = 0; k < K_DIM; ++k)
        acc2 = fmaf(asum[k], cw[k * C_DIM + c], acc2);  // coalesced over c
    out[b * C_DIM + c] = (S - acc2) * (1.0f / (float)K_DIM);
}

extern "C" void kernel_launch(void* const* d_in, const int* in_sizes, int n_in,
                              void* d_out, int out_size, void* d_ws, size_t ws_size,
                              hipStream_t stream) {
    const float* x     = (const float*)d_in[0];
    const float* cw    = (const float*)d_in[1];
    const float* scale = (const float*)d_in[2];
    float* out = (float*)d_out;
    float* ws  = (float*)d_ws;

    dim3 grid(NSLICE, B_DIM);
    ce_main<<<grid, 512, 0, stream>>>(x, cw, scale,
                                      ws + WS_SPART, ws + WS_APART);

    ce_final<<<B_DIM, 256, 0, stream>>>(out, cw,
                                        ws + WS_SPART, ws + WS_APART);
}

// Round 15
// 48.454 us; speedup vs baseline: 1.1212x; 1.1212x over previous
//
#include <hip/hip_runtime.h>
#include <hip/hip_bf16.h>
#include <math.h>

// Problem dims (fixed per reference)
#define B_DIM 32
#define C_DIM 256
#define K_DIM 32
#define N_DIM 4096   // 64*64
#define NSLICE 16    // 256-px slices (4 waves x 64 px)
#define NPART 64     // NSLICE * 4 waves: per-wave partial slots
#define RS 66        // padded dword stride per c-pair row (16 rows/tile)

typedef short v8s __attribute__((ext_vector_type(8)));   // 8 bf16
typedef float v4f __attribute__((ext_vector_type(4)));   // MFMA acc

// ws float offsets — every slot overwritten each call, no zeroing, no atomics
//   [0,      524288)  Spart [B][64][C]   (per-wave partials)
//   [524288, 589824)  a_part[B][64][K]
#define WS_SPART 0
#define WS_APART 524288

__device__ __forceinline__ unsigned pack_bf16(float lo, float hi) {
    union { __hip_bfloat16 h; unsigned short u; } a, b;
    a.h = __float2bfloat16(lo);
    b.h = __float2bfloat16(hi);
    return ((unsigned)b.u << 16) | a.u;
}

__global__ __launch_bounds__(256, 3)
void ce_main(const float* __restrict__ x,
             const float* __restrict__ cw,
             const float* __restrict__ scale,
             float* __restrict__ Spart,
             float* __restrict__ a_part) {
    __shared__ float buf[2][4][16 * RS];   // 33 KB: per-wave double-buffered tiles
    __shared__ unsigned cwl[K_DIM][132];   // 16.5 KB cw bf16-pairs (uint4-only access)
    __shared__ float f2s[4][64];           // per-wave f2 redistribution
    __shared__ float csl[64];              // c2[32] ++ scale[32]
    // total ~50.9 KB -> 3 blocks/CU

    const int tid   = threadIdx.x;
    const int wave  = tid >> 6;
    const int lane  = tid & 63;
    const int g     = lane >> 4;   // 16-lane group (consume roles)
    const int m     = lane & 15;
    const int ig    = lane >> 4;   // load role: c-row group
    const int q     = lane & 15;   // load role: px-quad
    const int slice = blockIdx.x;  // 0..15
    const int b     = blockIdx.y;  // 0..31

    const float* xw = x + (size_t)b * C_DIM * N_DIM + slice * 256 + wave * 64;

    // ---- step-0 x loads FIRST (HBM latency hides under the cw staging) ----
    float4 xv[8];
    #pragma unroll
    for (int j = 0; j < 4; ++j)
        #pragma unroll
        for (int r = 0; r < 2; ++r)
            xv[2 * j + r] = *(const float4*)(xw + (size_t)(2 * (4 * ig + j) + r) * N_DIM + 4 * q);

    // ---- fused prep: cw fp32 -> bf16 LDS + c2 + scale (once per block) ----
    {
        const int r = tid >> 3, c8 = tid & 7;   // k-row 0..31, col-chunk of 32 c
        float4 cv[8];
        #pragma unroll
        for (int j = 0; j < 8; ++j)
            cv[j] = ((const float4*)(cw + (size_t)r * C_DIM + c8 * 32))[j];
        float sq = 0.f;
        #pragma unroll
        for (int j = 0; j < 8; ++j) {
            sq = fmaf(cv[j].x, cv[j].x, sq);
            sq = fmaf(cv[j].y, cv[j].y, sq);
            sq = fmaf(cv[j].z, cv[j].z, sq);
            sq = fmaf(cv[j].w, cv[j].w, sq);
        }
        sq += __shfl_xor(sq, 1);
        sq += __shfl_xor(sq, 2);
        sq += __shfl_xor(sq, 4);
        if (c8 == 0) csl[r] = sq;
        if (tid < K_DIM) csl[32 + tid] = scale[tid];
        #pragma unroll
        for (int w = 0; w < 4; ++w) {
            uint4 o;
            o.x = pack_bf16(cv[2 * w].x, cv[2 * w].y);
            o.y = pack_bf16(cv[2 * w].z, cv[2 * w].w);
            o.z = pack_bf16(cv[2 * w + 1].x, cv[2 * w + 1].y);
            o.w = pack_bf16(cv[2 * w + 1].z, cv[2 * w + 1].w);
            *(uint4*)&cwl[r][16 * c8 + 4 * w] = o;
        }
    }
    __syncthreads();   // the ONLY barrier in this kernel

    // ---- hoist ALL A-fragments to registers (once; k = 16u+m, c-chunk 4s+g) ----
    uint4 afr[2][8];
    #pragma unroll
    for (int u = 0; u < 2; ++u)
        #pragma unroll
        for (int s = 0; s < 8; ++s)
            afr[u][s] = ((const uint4*)&cwl[16 * u + m][0])[4 * s + g];

    float* b0 = &buf[0][wave][0];
    float* b1 = &buf[1][wave][0];

    v4f acc[2][4];
    #pragma unroll
    for (int u = 0; u < 2; ++u)
        #pragma unroll
        for (int t = 0; t < 4; ++t) acc[u][t] = (v4f){0.f, 0.f, 0.f, 0.f};

    float f2q[4] = {0.f, 0.f, 0.f, 0.f};
    float sLo[8], sHi[8];

    // pack step 0 into tile0 (scalar unsigned LDS stores — proven type combo)
    #pragma unroll
    for (int j = 0; j < 4; ++j) {
        float4 r0 = xv[2 * j], r1 = xv[2 * j + 1];
        f2q[0] = fmaf(r0.x, r0.x, f2q[0]); f2q[0] = fmaf(r1.x, r1.x, f2q[0]);
        f2q[1] = fmaf(r0.y, r0.y, f2q[1]); f2q[1] = fmaf(r1.y, r1.y, f2q[1]);
        f2q[2] = fmaf(r0.z, r0.z, f2q[2]); f2q[2] = fmaf(r1.z, r1.z, f2q[2]);
        f2q[3] = fmaf(r0.w, r0.w, f2q[3]); f2q[3] = fmaf(r1.w, r1.w, f2q[3]);
        unsigned* dst = &((unsigned*)b0)[(4 * ig + j) * RS + 4 * q];
        dst[0] = pack_bf16(r0.x, r1.x);
        dst[1] = pack_bf16(r0.y, r1.y);
        dst[2] = pack_bf16(r0.z, r1.z);
        dst[3] = pack_bf16(r0.w, r1.w);
    }

    #pragma unroll
    for (int s = 0; s < 8; ++s) {
        float* cb = (s & 1) ? b1 : b0;
        float* nb = (s & 1) ? b0 : b1;

        // issue next step's x loads (dwordx4; consumed by the pack below)
        if (s < 7) {
            #pragma unroll
            for (int j = 0; j < 4; ++j)
                #pragma unroll
                for (int r = 0; r < 2; ++r)
                    xv[2 * j + r] = *(const float4*)(xw +
                        (size_t)(32 * (s + 1) + 2 * (4 * ig + j) + r) * N_DIM + 4 * q);
        }

        // B-frags (f) + 8 MFMA: D[k][px] += cw[k][c] * f[c][px]
        #pragma unroll
        for (int t = 0; t < 4; ++t) {
            union { unsigned d[4]; v8s v; } fb;
            #pragma unroll
            for (int h = 0; h < 4; ++h)
                fb.d[h] = ((const unsigned*)cb)[(4 * g + h) * RS + 16 * t + m];
            union { uint4 u; v8s v; } a0, a1;
            a0.u = afr[0][s]; a1.u = afr[1][s];
            acc[0][t] = __builtin_amdgcn_mfma_f32_16x16x32_bf16(a0.v, fb.v, acc[0][t], 0, 0, 0);
            acc[1][t] = __builtin_amdgcn_mfma_f32_16x16x32_bf16(a1.v, fb.v, acc[1][t], 0, 0, 0);
        }

        // S row sums from the staged tile: lane owns c-pair row m, px chunk 16g
        {
            float aLo = 0.f, aHi = 0.f;
            #pragma unroll
            for (int qq = 0; qq < 8; ++qq) {
                uint2 w = ((const uint2*)cb)[33 * m + 8 * g + qq];
                aLo += __uint_as_float(w.x << 16) + __uint_as_float(w.y << 16);
                aHi += __uint_as_float(w.x & 0xffff0000u) + __uint_as_float(w.y & 0xffff0000u);
            }
            aLo += __shfl_xor(aLo, 16); aLo += __shfl_xor(aLo, 32);
            aHi += __shfl_xor(aHi, 16); aHi += __shfl_xor(aHi, 32);
            sLo[s] = aLo; sHi[s] = aHi;
        }

        // pack the loads issued above into the next tile
        if (s < 7) {
            #pragma unroll
            for (int j = 0; j < 4; ++j) {
                float4 r0 = xv[2 * j], r1 = xv[2 * j + 1];
                f2q[0] = fmaf(r0.x, r0.x, f2q[0]); f2q[0] = fmaf(r1.x, r1.x, f2q[0]);
                f2q[1] = fmaf(r0.y, r0.y, f2q[1]); f2q[1] = fmaf(r1.y, r1.y, f2q[1]);
                f2q[2] = fmaf(r0.z, r0.z, f2q[2]); f2q[2] = fmaf(r1.z, r1.z, f2q[2]);
                f2q[3] = fmaf(r0.w, r0.w, f2q[3]); f2q[3] = fmaf(r1.w, r1.w, f2q[3]);
                unsigned* dst = &((unsigned*)nb)[(4 * ig + j) * RS + 4 * q];
                dst[0] = pack_bf16(r0.x, r1.x);
                dst[1] = pack_bf16(r0.y, r1.y);
                dst[2] = pack_bf16(r0.z, r1.z);
                dst[3] = pack_bf16(r0.w, r1.w);
            }
        }
    }

    // ---- epilogue (fully wave-local; per-wave partials go straight to global) ----
    // f2 totals per px: reduce over the 4 ig-lanes sharing a px-quad
    #pragma unroll
    for (int p = 0; p < 4; ++p) {
        f2q[p] += __shfl_xor(f2q[p], 16);
        f2q[p] += __shfl_xor(f2q[p], 32);
    }
    if (lane < 16) {
        f2s[wave][4 * q + 0] = f2q[0];
        f2s[wave][4 * q + 1] = f2q[1];
        f2s[wave][4 * q + 2] = f2q[2];
        f2s[wave][4 * q + 3] = f2q[3];
    }

    float c2v[2][4], scv[2][4];
    #pragma unroll
    for (int u = 0; u < 2; ++u)
        #pragma unroll
        for (int r = 0; r < 4; ++r) {
            int k = 16 * u + 4 * g + r;
            c2v[u][r] = csl[k];
            scv[u][r] = csl[32 + k];
        }

    float aacc[2][4] = {{0.f,0.f,0.f,0.f},{0.f,0.f,0.f,0.f}};
    #pragma unroll
    for (int t = 0; t < 4; ++t) {
        float f2t = f2s[wave][16 * t + m];   // px = 16t + m
        float L[2][4];
        float mx = -1e30f;
        #pragma unroll
        for (int u = 0; u < 2; ++u)
            #pragma unroll
            for (int r = 0; r < 4; ++r) {
                float d2 = f2t + c2v[u][r] - 2.f * acc[u][t][r];
                float dist = sqrtf(fmaxf(d2, 0.f));
                float Lv = -dist * scv[u][r];
                L[u][r] = Lv;
                mx = fmaxf(mx, Lv);
            }
        mx = fmaxf(mx, __shfl_xor(mx, 16));
        mx = fmaxf(mx, __shfl_xor(mx, 32));
        float e[2][4], ss = 0.f;
        #pragma unroll
        for (int u = 0; u < 2; ++u)
            #pragma unroll
            for (int r = 0; r < 4; ++r) {
                e[u][r] = __expf(L[u][r] - mx);
                ss += e[u][r];
            }
        ss += __shfl_xor(ss, 16);
        ss += __shfl_xor(ss, 32);
        float inv = 1.f / ss;
        #pragma unroll
        for (int u = 0; u < 2; ++u)
            #pragma unroll
            for (int r = 0; r < 4; ++r)
                aacc[u][r] = fmaf(e[u][r], inv, aacc[u][r]);
    }

    const int part = (b * NSLICE + slice) * 4 + wave;

    // reduce a over the 16 pixels (m lanes) of each group; write per-wave slot
    float* ap = a_part + (size_t)part * K_DIM;
    #pragma unroll
    for (int u = 0; u < 2; ++u)
        #pragma unroll
        for (int r = 0; r < 4; ++r) {
            float v = aacc[u][r];
            v += __shfl_xor(v, 1);
            v += __shfl_xor(v, 2);
            v += __shfl_xor(v, 4);
            v += __shfl_xor(v, 8);
            if (m == 0) ap[16 * u + 4 * g + r] = v;
        }

    // per-wave S partial straight to global
    float* Sp = Spart + (size_t)part * C_DIM;
    if (g == 0) {
        #pragma unroll
        for (int s = 0; s < 8; ++s) {
            Sp[32 * s + 2 * m]     = sLo[s];
            Sp[32 * s + 2 * m + 1] = sHi[s];
        }
    }
}

__global__ void ce_final(float* __restrict__ out,
                         const float* __restrict__ cw,
                         const float* __restrict__ Spart,
                         const float* __restrict__ a_part) {
    __shared__ float asum[K_DIM];
    const int b = blockIdx.x;
    const int c = threadIdx.x;

    if (c < K_DIM) {
        float a = 0.f;
        #pragma unroll
        for (int s = 0; s < NPART; ++s)
            a += a_part[((size_t)b * NPART + s) * K_DIM + c];
        asum[c] = a;
    }
    __syncthreads();

    float S = 0.f;
    #pragma unroll
    for (int s = 0; s < NPART; ++s)
        S += Spart[((size_t)b * NPART + s) * C_DIM + c];

    float acc2 = 0.f;
    #pragma unroll
    for (int k = 0; k < K_DIM; ++k)
        acc2 = fmaf(asum[k], cw[k * C_DIM + c], acc2);  // coalesced over c
    out[b * C_DIM + c] = (S - acc2) * (1.0f / (float)K_DIM);
}

extern "C" void kernel_launch(void* const* d_in, const int* in_sizes, int n_in,
                              void* d_out, int out_size, void* d_ws, size_t ws_size,
                              hipStream_t stream) {
    const float* x     = (const float*)d_in[0];
    const float* cw    = (const float*)d_in[1];
    const float* scale = (const float*)d_in[2];
    float* out = (float*)d_out;
    float* ws  = (float*)d_ws;

    dim3 grid(NSLICE, B_DIM);
    ce_main<<<grid, 256, 0, stream>>>(x, cw, scale,
                                      ws + WS_SPART, ws + WS_APART);

    ce_final<<<B_DIM, 256, 0, stream>>>(out, cw,
                                        ws + WS_SPART, ws + WS_APART);
}

// Round 16
// 40.796 us; speedup vs baseline: 1.3317x; 1.1877x over previous
//
#include <hip/hip_runtime.h>
#include <hip/hip_bf16.h>
#include <math.h>

// Problem dims (fixed per reference)
#define B_DIM 32
#define C_DIM 256
#define K_DIM 32
#define N_DIM 4096   // 64*64
#define NSLICE 16    // 256-px slices (4 waves x 64 px)
#define RS 66        // padded dword stride per c-pair row (16 rows/tile)

typedef short v8s __attribute__((ext_vector_type(8)));   // 8 bf16
typedef float v4f __attribute__((ext_vector_type(4)));   // MFMA acc

// ws float offsets — every slot overwritten each call, no zeroing, no atomics
//   [0,      131072)  Spart [B][16][C]
//   [131072, 147456)  a_part[B][16][K]
#define WS_SPART 0
#define WS_APART 131072

__device__ __forceinline__ unsigned pack_bf16(float lo, float hi) {
    union { __hip_bfloat16 h; unsigned short u; } a, b;
    a.h = __float2bfloat16(lo);
    b.h = __float2bfloat16(hi);
    return ((unsigned)b.u << 16) | a.u;
}

__global__ __launch_bounds__(256, 2)
void ce_main(const float* __restrict__ x,
             const float* __restrict__ cw,
             const float* __restrict__ scale,
             float* __restrict__ Spart,
             float* __restrict__ a_part) {
    __shared__ float buf[2][4][16 * RS];   // 33 KB: per-wave double-buffered tiles
    __shared__ unsigned cwl[K_DIM][132];   // 16.5 KB cw bf16-pairs (uint4-only access)
    __shared__ float sA[4][C_DIM];         // per-wave S partials
    __shared__ float awv[4][K_DIM];        // per-wave a partials
    __shared__ float f2s[4][64];           // per-wave f2 redistribution
    __shared__ float csl[64];              // c2[32] ++ scale[32]

    const int tid   = threadIdx.x;
    const int wave  = tid >> 6;
    const int lane  = tid & 63;
    const int g     = lane >> 4;   // 16-lane group (consume roles)
    const int m     = lane & 15;
    const int ig    = lane >> 4;   // load role: c-row group
    const int q     = lane & 15;   // load role: px-quad
    const int slice = blockIdx.x;  // 0..15
    const int b     = blockIdx.y;  // 0..31

    const float* xw = x + (size_t)b * C_DIM * N_DIM + slice * 256 + wave * 64;

    // ---- step-0 x loads FIRST (HBM latency hides under the cw staging) ----
    float4 xv[8];
    #pragma unroll
    for (int j = 0; j < 4; ++j)
        #pragma unroll
        for (int r = 0; r < 2; ++r)
            xv[2 * j + r] = *(const float4*)(xw + (size_t)(2 * (4 * ig + j) + r) * N_DIM + 4 * q);

    // ---- fused prep: cw fp32 -> bf16 LDS + c2 + scale (once per block) ----
    {
        const int r = tid >> 3, c8 = tid & 7;   // k-row 0..31, col-chunk of 32 c
        float4 cv[8];
        #pragma unroll
        for (int j = 0; j < 8; ++j)
            cv[j] = ((const float4*)(cw + (size_t)r * C_DIM + c8 * 32))[j];
        float sq = 0.f;
        #pragma unroll
        for (int j = 0; j < 8; ++j) {
            sq = fmaf(cv[j].x, cv[j].x, sq);
            sq = fmaf(cv[j].y, cv[j].y, sq);
            sq = fmaf(cv[j].z, cv[j].z, sq);
            sq = fmaf(cv[j].w, cv[j].w, sq);
        }
        sq += __shfl_xor(sq, 1);
        sq += __shfl_xor(sq, 2);
        sq += __shfl_xor(sq, 4);
        if (c8 == 0) csl[r] = sq;
        if (tid < K_DIM) csl[32 + tid] = scale[tid];
        #pragma unroll
        for (int w = 0; w < 4; ++w) {
            uint4 o;
            o.x = pack_bf16(cv[2 * w].x, cv[2 * w].y);
            o.y = pack_bf16(cv[2 * w].z, cv[2 * w].w);
            o.z = pack_bf16(cv[2 * w + 1].x, cv[2 * w + 1].y);
            o.w = pack_bf16(cv[2 * w + 1].z, cv[2 * w + 1].w);
            *(uint4*)&cwl[r][16 * c8 + 4 * w] = o;
        }
    }
    __syncthreads();

    // ---- hoist ALL A-fragments to registers (once; k = 16u+m, c-chunk 4s+g) ----
    uint4 afr[2][8];
    #pragma unroll
    for (int u = 0; u < 2; ++u)
        #pragma unroll
        for (int s = 0; s < 8; ++s)
            afr[u][s] = ((const uint4*)&cwl[16 * u + m][0])[4 * s + g];

    float* b0 = &buf[0][wave][0];
    float* b1 = &buf[1][wave][0];

    v4f acc[2][4];
    #pragma unroll
    for (int u = 0; u < 2; ++u)
        #pragma unroll
        for (int t = 0; t < 4; ++t) acc[u][t] = (v4f){0.f, 0.f, 0.f, 0.f};

    float f2q[4] = {0.f, 0.f, 0.f, 0.f};
    float sLo[8], sHi[8];

    // pack step 0 into tile0 (scalar unsigned LDS stores — proven type combo)
    #pragma unroll
    for (int j = 0; j < 4; ++j) {
        float4 r0 = xv[2 * j], r1 = xv[2 * j + 1];
        f2q[0] = fmaf(r0.x, r0.x, f2q[0]); f2q[0] = fmaf(r1.x, r1.x, f2q[0]);
        f2q[1] = fmaf(r0.y, r0.y, f2q[1]); f2q[1] = fmaf(r1.y, r1.y, f2q[1]);
        f2q[2] = fmaf(r0.z, r0.z, f2q[2]); f2q[2] = fmaf(r1.z, r1.z, f2q[2]);
        f2q[3] = fmaf(r0.w, r0.w, f2q[3]); f2q[3] = fmaf(r1.w, r1.w, f2q[3]);
        unsigned* dst = &((unsigned*)b0)[(4 * ig + j) * RS + 4 * q];
        dst[0] = pack_bf16(r0.x, r1.x);
        dst[1] = pack_bf16(r0.y, r1.y);
        dst[2] = pack_bf16(r0.z, r1.z);
        dst[3] = pack_bf16(r0.w, r1.w);
    }

    #pragma unroll
    for (int s = 0; s < 8; ++s) {
        float* cb = (s & 1) ? b1 : b0;
        float* nb = (s & 1) ? b0 : b1;

        // issue next step's x loads (dwordx4; consumed by the pack below)
        if (s < 7) {
            #pragma unroll
            for (int j = 0; j < 4; ++j)
                #pragma unroll
                for (int r = 0; r < 2; ++r)
                    xv[2 * j + r] = *(const float4*)(xw +
                        (size_t)(32 * (s + 1) + 2 * (4 * ig + j) + r) * N_DIM + 4 * q);
        }

        // B-frags (f) + 8 MFMA: D[k][px] += cw[k][c] * f[c][px]
        #pragma unroll
        for (int t = 0; t < 4; ++t) {
            union { unsigned d[4]; v8s v; } fb;
            #pragma unroll
            for (int h = 0; h < 4; ++h)
                fb.d[h] = ((const unsigned*)cb)[(4 * g + h) * RS + 16 * t + m];
            union { uint4 u; v8s v; } a0, a1;
            a0.u = afr[0][s]; a1.u = afr[1][s];
            acc[0][t] = __builtin_amdgcn_mfma_f32_16x16x32_bf16(a0.v, fb.v, acc[0][t], 0, 0, 0);
            acc[1][t] = __builtin_amdgcn_mfma_f32_16x16x32_bf16(a1.v, fb.v, acc[1][t], 0, 0, 0);
        }

        // S row sums from the staged tile: lane owns c-pair row m, px chunk 16g
        {
            float aLo = 0.f, aHi = 0.f;
            #pragma unroll
            for (int qq = 0; qq < 8; ++qq) {
                uint2 w = ((const uint2*)cb)[33 * m + 8 * g + qq];
                aLo += __uint_as_float(w.x << 16) + __uint_as_float(w.y << 16);
                aHi += __uint_as_float(w.x & 0xffff0000u) + __uint_as_float(w.y & 0xffff0000u);
            }
            aLo += __shfl_xor(aLo, 16); aLo += __shfl_xor(aLo, 32);
            aHi += __shfl_xor(aHi, 16); aHi += __shfl_xor(aHi, 32);
            sLo[s] = aLo; sHi[s] = aHi;
        }

        // pack the loads issued above into the next tile
        if (s < 7) {
            #pragma unroll
            for (int j = 0; j < 4; ++j) {
                float4 r0 = xv[2 * j], r1 = xv[2 * j + 1];
                f2q[0] = fmaf(r0.x, r0.x, f2q[0]); f2q[0] = fmaf(r1.x, r1.x, f2q[0]);
                f2q[1] = fmaf(r0.y, r0.y, f2q[1]); f2q[1] = fmaf(r1.y, r1.y, f2q[1]);
                f2q[2] = fmaf(r0.z, r0.z, f2q[2]); f2q[2] = fmaf(r1.z, r1.z, f2q[2]);
                f2q[3] = fmaf(r0.w, r0.w, f2q[3]); f2q[3] = fmaf(r1.w, r1.w, f2q[3]);
                unsigned* dst = &((unsigned*)nb)[(4 * ig + j) * RS + 4 * q];
                dst[0] = pack_bf16(r0.x, r1.x);
                dst[1] = pack_bf16(r0.y, r1.y);
                dst[2] = pack_bf16(r0.z, r1.z);
                dst[3] = pack_bf16(r0.w, r1.w);
            }
        }
    }

    // ---- epilogue: softmax over k (4-lane groups share a pixel) ----
    // f2 totals per px: reduce over the 4 ig-lanes sharing a px-quad
    #pragma unroll
    for (int p = 0; p < 4; ++p) {
        f2q[p] += __shfl_xor(f2q[p], 16);
        f2q[p] += __shfl_xor(f2q[p], 32);
    }
    if (lane < 16) {
        f2s[wave][4 * q + 0] = f2q[0];
        f2s[wave][4 * q + 1] = f2q[1];
        f2s[wave][4 * q + 2] = f2q[2];
        f2s[wave][4 * q + 3] = f2q[3];
    }

    float c2v[2][4], scv[2][4];
    #pragma unroll
    for (int u = 0; u < 2; ++u)
        #pragma unroll
        for (int r = 0; r < 4; ++r) {
            int k = 16 * u + 4 * g + r;
            c2v[u][r] = csl[k];
            scv[u][r] = csl[32 + k];
        }

    float aacc[2][4] = {{0.f,0.f,0.f,0.f},{0.f,0.f,0.f,0.f}};
    #pragma unroll
    for (int t = 0; t < 4; ++t) {
        float f2t = f2s[wave][16 * t + m];   // px = 16t + m
        float L[2][4];
        float mx = -1e30f;
        #pragma unroll
        for (int u = 0; u < 2; ++u)
            #pragma unroll
            for (int r = 0; r < 4; ++r) {
                float d2 = f2t + c2v[u][r] - 2.f * acc[u][t][r];
                float dist = sqrtf(fmaxf(d2, 0.f));
                float Lv = -dist * scv[u][r];
                L[u][r] = Lv;
                mx = fmaxf(mx, Lv);
            }
        mx = fmaxf(mx, __shfl_xor(mx, 16));
        mx = fmaxf(mx, __shfl_xor(mx, 32));
        float e[2][4], ss = 0.f;
        #pragma unroll
        for (int u = 0; u < 2; ++u)
            #pragma unroll
            for (int r = 0; r < 4; ++r) {
                e[u][r] = __expf(L[u][r] - mx);
                ss += e[u][r];
            }
        ss += __shfl_xor(ss, 16);
        ss += __shfl_xor(ss, 32);
        float inv = 1.f / ss;
        #pragma unroll
        for (int u = 0; u < 2; ++u)
            #pragma unroll
            for (int r = 0; r < 4; ++r)
                aacc[u][r] = fmaf(e[u][r], inv, aacc[u][r]);
    }

    // reduce a over the 16 pixels (m lanes) of each group
    #pragma unroll
    for (int u = 0; u < 2; ++u)
        #pragma unroll
        for (int r = 0; r < 4; ++r) {
            float v = aacc[u][r];
            v += __shfl_xor(v, 1);
            v += __shfl_xor(v, 2);
            v += __shfl_xor(v, 4);
            v += __shfl_xor(v, 8);
            if (m == 0) awv[wave][16 * u + 4 * g + r] = v;
        }

    if (g == 0) {
        #pragma unroll
        for (int s = 0; s < 8; ++s) {
            sA[wave][32 * s + 2 * m]     = sLo[s];
            sA[wave][32 * s + 2 * m + 1] = sHi[s];
        }
    }
    __syncthreads();

    float Ssum = sA[0][tid] + sA[1][tid] + sA[2][tid] + sA[3][tid];
    Spart[((size_t)b * NSLICE + slice) * C_DIM + tid] = Ssum;
    if (tid < K_DIM)
        a_part[((size_t)b * NSLICE + slice) * K_DIM + tid] =
            awv[0][tid] + awv[1][tid] + awv[2][tid] + awv[3][tid];
}

__global__ void ce_final(float* __restrict__ out,
                         const float* __restrict__ cw,
                         const float* __restrict__ Spart,
                         const float* __restrict__ a_part) {
    __shared__ float asum[K_DIM];
    const int b = blockIdx.x;
    const int c = threadIdx.x;

    if (c < K_DIM) {
        float a = 0.f;
        #pragma unroll
        for (int s = 0; s < NSLICE; ++s)
            a += a_part[((size_t)b * NSLICE + s) * K_DIM + c];
        asum[c] = a;
    }
    __syncthreads();

    float S = 0.f;
    #pragma unroll
    for (int s = 0; s < NSLICE; ++s)
        S += Spart[((size_t)b * NSLICE + s) * C_DIM + c];

    float acc2 = 0.f;
    #pragma unroll
    for (int k = 0; k < K_DIM; ++k)
        acc2 = fmaf(asum[k], cw[k * C_DIM + c], acc2);  // coalesced over c
    out[b * C_DIM + c] = (S - acc2) * (1.0f / (float)K_DIM);
}

extern "C" void kernel_launch(void* const* d_in, const int* in_sizes, int n_in,
                              void* d_out, int out_size, void* d_ws, size_t ws_size,
                              hipStream_t stream) {
    const float* x     = (const float*)d_in[0];
    const float* cw    = (const float*)d_in[1];
    const float* scale = (const float*)d_in[2];
    float* out = (float*)d_out;
    float* ws  = (float*)d_ws;

    dim3 grid(NSLICE, B_DIM);
    ce_main<<<grid, 256, 0, stream>>>(x, cw, scale,
                                      ws + WS_SPART, ws + WS_APART);

    ce_final<<<B_DIM, 256, 0, stream>>>(out, cw,
                                        ws + WS_SPART, ws + WS_APART);
}